// Round 5
// baseline (204.936 us; speedup 1.0000x reference)
//
#include <hip/hip_runtime.h>
#include <math.h>

#define NB 8      // NUM_BATCHES
#define C  256    // channels
#define CR 64     // C / r

#define POOL_BLOCKS  512
#define SCALE_BLOCKS 2048

typedef float vf4 __attribute__((ext_vector_type(4)));

// ---------------------------------------------------------------------------
// Kernel 1 (fused pool + MLP):
//  phase 1: per-batch sums in registers (one wave per 4-row group, 4 KB
//           contiguous NT streaming; wave-uniform bid -> branch-free
//           predicated FMA into vf4 acc[8]).
//  phase 2: per-block LDS merge of the 4 wave copies (conflict-free b128).
//  phase 3: atomicAdd block partial into gsums/gcnts (device-scope, depth
//           = POOL_BLOCKS per address, parallel across 2056 addresses).
//  phase 4: last-block-done ticket: the final block re-reads gsums/gcnts
//           (agent-scope atomic loads after threadfence) and computes the
//           tiny MLP -> y. Saves 2 dispatches + 12 MB partials traffic.
// ---------------------------------------------------------------------------
__global__ __launch_bounds__(256) void pool_mlp_kernel(
    const float* __restrict__ x,      // [N, 256]
    const int*   __restrict__ bids,   // [N]
    const float* __restrict__ W1,     // [256][64]
    const float* __restrict__ b1,     // [64]
    const float* __restrict__ W2,     // [64][256]
    const float* __restrict__ b2,     // [256]
    float*       __restrict__ gsums,  // [8][256] (pre-zeroed)
    float*       __restrict__ gcnts,  // [8]      (pre-zeroed)
    int*         __restrict__ counter,// [1]      (pre-zeroed)
    float*       __restrict__ y,      // [8][256] out
    int N)
{
    __shared__ float lsum[4][NB][C];   // 32 KB (reused as pooled/h in phase 4)
    __shared__ float lcnt[4][NB];
    __shared__ int   lastFlag;

    const int tid  = threadIdx.x;
    const int wid  = tid >> 6;
    const int lane = tid & 63;

    vf4   acc[NB];
    float cnt[NB];
    #pragma unroll
    for (int b = 0; b < NB; ++b) { acc[b] = (vf4){0.f,0.f,0.f,0.f}; cnt[b] = 0.f; }

    const int gwave   = blockIdx.x * 4 + wid;
    const int totw    = POOL_BLOCKS * 4;
    const int ngroups = N >> 2;

    for (int g = gwave; g < ngroups; g += totw) {
        const size_t r0 = (size_t)g * 4;
        const int b0 = __builtin_amdgcn_readfirstlane(bids[r0 + 0]);
        const int b1_ = __builtin_amdgcn_readfirstlane(bids[r0 + 1]);
        const int b2_ = __builtin_amdgcn_readfirstlane(bids[r0 + 2]);
        const int b3_ = __builtin_amdgcn_readfirstlane(bids[r0 + 3]);
        const vf4 v0 = __builtin_nontemporal_load(((const vf4*)(x + (r0 + 0) * C)) + lane);
        const vf4 v1 = __builtin_nontemporal_load(((const vf4*)(x + (r0 + 1) * C)) + lane);
        const vf4 v2 = __builtin_nontemporal_load(((const vf4*)(x + (r0 + 2) * C)) + lane);
        const vf4 v3 = __builtin_nontemporal_load(((const vf4*)(x + (r0 + 3) * C)) + lane);
        #pragma unroll
        for (int b = 0; b < NB; ++b) {
            const float m0 = (b0  == b) ? 1.f : 0.f;
            const float m1 = (b1_ == b) ? 1.f : 0.f;
            const float m2 = (b2_ == b) ? 1.f : 0.f;
            const float m3 = (b3_ == b) ? 1.f : 0.f;
            acc[b] += v0 * m0;
            acc[b] += v1 * m1;
            acc[b] += v2 * m2;
            acc[b] += v3 * m3;
            cnt[b] += m0 + m1 + m2 + m3;
        }
    }
    if (gwave == 0) {  // leftover rows if N % 4 != 0 (none at N=262144)
        for (int row = ngroups * 4; row < N; ++row) {
            const int bb = __builtin_amdgcn_readfirstlane(bids[row]);
            const vf4 v = ((const vf4*)(x + (size_t)row * C))[lane];
            #pragma unroll
            for (int b = 0; b < NB; ++b) {
                const float m = (bb == b) ? 1.f : 0.f;
                acc[b] += v * m;
                cnt[b] += m;
            }
        }
    }

    // phase 2: conflict-free b128 LDS merge
    #pragma unroll
    for (int b = 0; b < NB; ++b)
        ((vf4*)&lsum[wid][b][0])[lane] = acc[b];
    if (lane == 0) {
        #pragma unroll
        for (int b = 0; b < NB; ++b) lcnt[wid][b] = cnt[b];
    }
    __syncthreads();

    // phase 3: one atomicAdd per element per block
    for (int i = tid; i < NB * C; i += 256) {
        float s = lsum[0][0][i] + lsum[1][0][i] + lsum[2][0][i] + lsum[3][0][i];
        atomicAdd(&gsums[i], s);
    }
    if (tid < NB) {
        float s = lcnt[0][tid] + lcnt[1][tid] + lcnt[2][tid] + lcnt[3][tid];
        atomicAdd(&gcnts[tid], s);
    }

    // phase 4: last-block-done -> MLP
    __threadfence();                       // complete our atomics (vmcnt drain)
    if (tid == 0)
        lastFlag = (atomicAdd(counter, 1) == POOL_BLOCKS - 1);
    __syncthreads();
    if (!lastFlag) return;
    __threadfence();                       // acquire side

    float* pooled = &lsum[0][0][0];        // reuse LDS: [8][256]
    float* h      = &lsum[2][0][0];        // reuse LDS: [8][64]
    float* cn     = &lcnt[0][0];           // [8]

    if (tid < NB) {
        const float c = __hip_atomic_load(&gcnts[tid], __ATOMIC_RELAXED,
                                          __HIP_MEMORY_SCOPE_AGENT);
        cn[tid] = fmaxf(c, 1.f);
    }
    __syncthreads();
    for (int i = tid; i < NB * C; i += 256) {
        const float s = __hip_atomic_load(&gsums[i], __ATOMIC_RELAXED,
                                          __HIP_MEMORY_SCOPE_AGENT);
        pooled[i] = s / cn[i >> 8];
    }
    __syncthreads();

    for (int o = tid; o < NB * CR; o += 256) {       // h = relu(pooled@W1+b1)
        const int b = o >> 6, j = o & 63;
        float a = b1[j];
        #pragma unroll 4
        for (int k = 0; k < C; ++k) a = fmaf(pooled[b * C + k], W1[k * CR + j], a);
        h[o] = fmaxf(a, 0.f);
    }
    __syncthreads();

    for (int o = tid; o < NB * C; o += 256) {        // y = sigmoid(h@W2+b2)
        const int b = o >> 8, j = o & 255;
        float a = b2[j];
        #pragma unroll
        for (int k = 0; k < CR; ++k) a = fmaf(h[b * CR + k], W2[k * C + j], a);
        y[o] = 1.f / (1.f + __expf(-a));
    }
}

// ---------------------------------------------------------------------------
// Kernel 2: out[row,:] = y[bids[row],:] * x[row,:]. One wave per 4-row group
// (4 KB contiguous read + 4 KB write), FORWARD order (R4's reversal hurt),
// y cached in LDS (uniform bid -> 2-way b128 = free), NT load/store.
// ---------------------------------------------------------------------------
__global__ __launch_bounds__(256) void scale_kernel(
    const float* __restrict__ x,     // [N, 256]
    const int*   __restrict__ bids,  // [N]
    const float* __restrict__ y,     // [8][256]
    float*       __restrict__ out,   // [N, 256]
    int N)
{
    __shared__ float ly[NB][C];      // 8 KB
    const int tid = threadIdx.x;
    for (int i = tid; i < NB * C; i += 256) (&ly[0][0])[i] = y[i];
    __syncthreads();

    const int wid  = tid >> 6;
    const int lane = tid & 63;
    const int gwave   = blockIdx.x * 4 + wid;
    const int totw    = SCALE_BLOCKS * 4;
    const int ngroups = N >> 2;

    for (int g = gwave; g < ngroups; g += totw) {
        const size_t r0 = (size_t)g * 4;
        const int b0 = __builtin_amdgcn_readfirstlane(bids[r0 + 0]);
        const int b1 = __builtin_amdgcn_readfirstlane(bids[r0 + 1]);
        const int b2 = __builtin_amdgcn_readfirstlane(bids[r0 + 2]);
        const int b3 = __builtin_amdgcn_readfirstlane(bids[r0 + 3]);
        const vf4 v0 = __builtin_nontemporal_load(((const vf4*)(x + (r0 + 0) * C)) + lane);
        const vf4 v1 = __builtin_nontemporal_load(((const vf4*)(x + (r0 + 1) * C)) + lane);
        const vf4 v2 = __builtin_nontemporal_load(((const vf4*)(x + (r0 + 2) * C)) + lane);
        const vf4 v3 = __builtin_nontemporal_load(((const vf4*)(x + (r0 + 3) * C)) + lane);
        const vf4 g0 = ((const vf4*)&ly[b0][0])[lane];
        const vf4 g1 = ((const vf4*)&ly[b1][0])[lane];
        const vf4 g2 = ((const vf4*)&ly[b2][0])[lane];
        const vf4 g3 = ((const vf4*)&ly[b3][0])[lane];
        __builtin_nontemporal_store(v0 * g0, ((vf4*)(out + (r0 + 0) * C)) + lane);
        __builtin_nontemporal_store(v1 * g1, ((vf4*)(out + (r0 + 1) * C)) + lane);
        __builtin_nontemporal_store(v2 * g2, ((vf4*)(out + (r0 + 2) * C)) + lane);
        __builtin_nontemporal_store(v3 * g3, ((vf4*)(out + (r0 + 3) * C)) + lane);
    }
    if (gwave == 0) {
        for (int row = ngroups * 4; row < N; ++row) {
            const int bb = __builtin_amdgcn_readfirstlane(bids[row]);
            const vf4 v  = ((const vf4*)(x + (size_t)row * C))[lane];
            const vf4 gg = ((const vf4*)&ly[bb][0])[lane];
            ((vf4*)(out + (size_t)row * C))[lane] = v * gg;
        }
    }
}

extern "C" void kernel_launch(void* const* d_in, const int* in_sizes, int n_in,
                              void* d_out, int out_size, void* d_ws, size_t ws_size,
                              hipStream_t stream)
{
    const float* x    = (const float*)d_in[0];
    const int*   bids = (const int*)  d_in[1];
    const float* W1   = (const float*)d_in[2];
    const float* b1   = (const float*)d_in[3];
    const float* W2   = (const float*)d_in[4];
    const float* b2   = (const float*)d_in[5];
    float* out = (float*)d_out;

    const int N = in_sizes[1];           // 262144

    // ws layout (floats): gsums[2048] | gcnts[8] | counter+pad[8] | gy[2048]
    float* gsums   = (float*)d_ws;
    float* gcnts   = gsums + NB * C;
    int*   counter = (int*)(gcnts + NB);
    float* gy      = gcnts + NB + 8;

    // zero gsums + gcnts + counter every call (ws is not re-poisoned)
    hipMemsetAsync(d_ws, 0, (NB * C + NB + 8) * sizeof(float), stream);

    pool_mlp_kernel<<<POOL_BLOCKS, 256, 0, stream>>>(
        x, bids, W1, b1, W2, b2, gsums, gcnts, counter, gy, N);
    scale_kernel<<<SCALE_BLOCKS, 256, 0, stream>>>(x, bids, gy, out, N);
}